// Round 5
// baseline (236.702 us; speedup 1.0000x reference)
//
#include <hip/hip_runtime.h>
#include <math.h>

#define B_ 2048
#define N_ 256
#define R_ (B_*N_)
#define MU_ 0.1f
#define SIGMA_ 0.2f
#define TILE_M 32
#define GRID_MLP 512
#define ITERS (R_ / TILE_M / GRID_MLP)   // 32

typedef __attribute__((ext_vector_type(8))) short bf16x8;
typedef __attribute__((ext_vector_type(4))) float f32x4;

__device__ __forceinline__ unsigned short f2bf(float x) {  // RNE (weights only)
    union { float f; unsigned u; } v; v.f = x;
    unsigned r = v.u + 0x7fffu + ((v.u >> 16) & 1u);
    return (unsigned short)(r >> 16);
}

// ---- convert fW1/gW1 (256x256 f32, k-major) to bf16 MFMA fragments ----
// short idx = ((kk*16 + ct)*64 + lane)*8 + j ; holds W1[k = kk*32+(lane>>4)*8+j][c = ct*16+(lane&15)]
// (same index map serves as A-frag of W1^T for the transposed GEMM)
__global__ void prep_weights(const float* __restrict__ fW1, const float* __restrict__ gW1,
                             unsigned short* __restrict__ wswz) {
    int idx = blockIdx.x * 256 + threadIdx.x;
    if (idx >= 2 * 65536) return;
    int m = idx >> 16, r = idx & 65535;
    int j = r & 7, lane = (r >> 3) & 63, frag = r >> 9;
    int kk = frag >> 4, ct = frag & 15;
    int k = kk * 32 + (lane >> 4) * 8 + j;
    int c = ct * 16 + (lane & 15);
    const float* W = m ? gW1 : fW1;
    wswz[idx] = f2bf(W[k * 256 + c]);
}

// ---- trajectory via wave-parallel prefix-product scan: one wave per batch row ----
__global__ void traj_kernel(const float* __restrict__ ts, const float* __restrict__ x0,
                            const float* __restrict__ eps, float* __restrict__ xs,
                            float* __restrict__ fv) {
    int gid = blockIdx.x * 256 + threadIdx.x;
    int b = gid >> 6, lane = gid & 63;
    int n0 = lane * 4;

    float t0 = ts[n0], t1 = ts[n0 + 1], t2 = ts[n0 + 2], t3 = ts[n0 + 3];
    float t4 = (n0 + 4 < N_) ? ts[n0 + 4] : t3;          // lane 63: h3 = 0
    float h0 = t1 - t0, h1 = t2 - t1, h2 = t3 - t2, h3 = t4 - t3;
    float s0 = sqrtf(h0), s1 = sqrtf(h1), s2 = sqrtf(h2), s3 = sqrtf(h3);

    const float4* e4 = (const float4*)(eps + (size_t)(b * N_ + n0) * 2);
    float4 ea = e4[0], eb = e4[1];
    float f0a = 1.f + MU_ * h0 + SIGMA_ * (ea.x * s0);
    float f0b = 1.f + MU_ * h0 + SIGMA_ * (ea.y * s0);
    float f1a = 1.f + MU_ * h1 + SIGMA_ * (ea.z * s1);
    float f1b = 1.f + MU_ * h1 + SIGMA_ * (ea.w * s1);
    float f2a = 1.f + MU_ * h2 + SIGMA_ * (eb.x * s2);
    float f2b = 1.f + MU_ * h2 + SIGMA_ * (eb.y * s2);
    float f3a = 1.f + MU_ * h3 + SIGMA_ * (eb.z * s3);
    float f3b = 1.f + MU_ * h3 + SIGMA_ * (eb.w * s3);

    float Pa = f0a * f1a * f2a * f3a;
    float Pb = f0b * f1b * f2b * f3b;
    float Sa = Pa, Sb = Pb;
#pragma unroll
    for (int d = 1; d < 64; d <<= 1) {
        float va = __shfl_up(Sa, d);
        float vb = __shfl_up(Sb, d);
        if (lane >= d) { Sa *= va; Sb *= vb; }
    }
    float Ea = __shfl_up(Sa, 1);
    float Eb = __shfl_up(Sb, 1);
    if (lane == 0) { Ea = 1.f; Eb = 1.f; }

    float x0a = x0[2 * b], x0b = x0[2 * b + 1];
    float xa0 = x0a * Ea, xb0 = x0b * Eb;
    float xa1 = xa0 * f0a, xb1 = xb0 * f0b;
    float xa2 = xa1 * f1a, xb2 = xb1 * f1b;
    float xa3 = xa2 * f2a, xb3 = xb2 * f2b;

    float4* xsv = (float4*)(xs + (size_t)(b * N_ + n0) * 2);
    xsv[0] = make_float4(xa0, xb0, xa1, xb1);
    xsv[1] = make_float4(xa2, xb2, xa3, xb3);
    if (lane == 63) fv[b] = xa3 * xa3 + xb3 * xb3;
}

// ---- fused MLP, transposed GEMM: D = W1^T(A, resident regs) @ h0^T(B, LDS) ----
// 256 threads / 4 waves; wave w owns cs [64w,64w+64); TILE_M=32 samples per tile.
// amdgpu_waves_per_eu(2,2): pin allocator to the 256-VGPR budget so afrag stays resident
// (round-4 evidence: heuristic squeezed to 128 VGPR and spilled afrag -> 19MB/dispatch scratch).
template<int MLP>
__global__ __launch_bounds__(256) __attribute__((amdgpu_waves_per_eu(2, 2))) void mlp_kernel(
        const float* __restrict__ ts, const float* __restrict__ eps, const float* __restrict__ xs,
        const unsigned short* __restrict__ wswz,
        const float* __restrict__ W0, const float* __restrict__ b0,
        const float* __restrict__ b1, const float* __restrict__ W2, const float* __restrict__ b2,
        float* __restrict__ outp) {

    __shared__ __align__(16) unsigned short h0s[TILE_M * 256];   // 16KB, XOR-swizzled rows
    __shared__ float tss[2][TILE_M], txs1[2][TILE_M], txs2[2][TILE_M];
    __shared__ float dws0[2][TILE_M], dws1[2][TILE_M];
    __shared__ float red[4][TILE_M];

    const int tid  = threadIdx.x;
    const int lane = tid & 63;
    const int w    = tid >> 6;       // wave 0..3
    const int arow = lane & 15;      // sample col within 16-tile
    const int rg   = lane >> 4;      // k-group / c-subgroup

    // layer0: this thread computes cols [c0,c0+4) for rows [8w, 8w+8)
    const int c0 = (tid & 63) * 4;
    f32x4 w0t = *(const f32x4*)(W0 + c0);
    f32x4 w0x = *(const f32x4*)(W0 + 256 + c0);
    f32x4 w0y = *(const f32x4*)(W0 + 512 + c0);
    f32x4 w0bv = *(const f32x4*)(b0 + c0);

    // per-lane layer1 bias + layer2 weights for c = 64w + 16ct + 4rg + {0..3}
    f32x4 b1v[4], w20v[4], w21v[4];
#pragma unroll
    for (int ct = 0; ct < 4; ++ct) {
        int c = w * 64 + ct * 16 + rg * 4;
        b1v[ct] = *(const f32x4*)(b1 + c);
        if (MLP) {
            f32x4 lo = *(const f32x4*)(W2 + 2 * c);
            f32x4 hi = *(const f32x4*)(W2 + 2 * c + 4);
            w20v[ct] = (f32x4){lo[0], lo[2], hi[0], hi[2]};
            w21v[ct] = (f32x4){lo[1], lo[3], hi[1], hi[3]};
        } else {
            w20v[ct] = *(const f32x4*)(W2 + c);
            w21v[ct] = (f32x4){0.f, 0.f, 0.f, 0.f};
        }
    }
    const float b20 = b2[0];
    const float b21 = MLP ? b2[1] : 0.f;

    // resident A-fragments of W1^T: 8 kk x 4 ct x 4 VGPR = 128 VGPRs
    bf16x8 afrag[8][4];
    const bf16x8* wsw8 = (const bf16x8*)wswz;
#pragma unroll
    for (int kk = 0; kk < 8; ++kk)
#pragma unroll
        for (int ct = 0; ct < 4; ++ct)
            afrag[kk][ct] = wsw8[(kk * 16 + (w * 4 + ct)) * 64 + lane];

    // prefetch tile 0 stage data
    float p_x1 = 0.f, p_x2 = 0.f, p_t = 0.f, p_tn = 0.f, p_e0 = 0.f, p_e1 = 0.f;
    if (tid < TILE_M) {
        int r = blockIdx.x * TILE_M + tid, n = r & (N_ - 1);
        float2 xv = ((const float2*)xs)[r];
        p_x1 = xv.x; p_x2 = xv.y;
        p_t = ts[n]; p_tn = (n < N_ - 1) ? ts[n + 1] : ts[n];
        if (MLP) { float2 ev = ((const float2*)eps)[r]; p_e0 = ev.x; p_e1 = ev.y; }
    }

    for (int it = 0; it < ITERS; ++it) {
        const int rowbase = (blockIdx.x + it * GRID_MLP) * TILE_M;
        const int sb = it & 1;
        if (tid < TILE_M) {
            tss[sb][tid] = p_t; txs1[sb][tid] = p_x1; txs2[sb][tid] = p_x2;
            if (MLP) {
                float sdt = sqrtf(p_tn - p_t);
                dws0[sb][tid] = p_e0 * sdt; dws1[sb][tid] = p_e1 * sdt;
            }
        }
        __syncthreads();                                 // sync1: stage[sb] visible
        if (tid < TILE_M && it + 1 < ITERS) {            // prefetch next tile
            int r = rowbase + GRID_MLP * TILE_M + tid, n = r & (N_ - 1);
            float2 xv = ((const float2*)xs)[r];
            p_x1 = xv.x; p_x2 = xv.y;
            p_t = ts[n]; p_tn = (n < N_ - 1) ? ts[n + 1] : ts[n];
            if (MLP) { float2 ev = ((const float2*)eps)[r]; p_e0 = ev.x; p_e1 = ev.y; }
        }
        // layer0: 8 rows x 4 cols per thread, truncation-pack to bf16
#pragma unroll
        for (int i = 0; i < 8; ++i) {
            int r = w * 8 + i;
            float t = tss[sb][r], x1 = txs1[sb][r], x2 = txs2[sb][r];
            f32x4 h;
#pragma unroll
            for (int j = 0; j < 4; ++j)
                h[j] = fmaf(t, w0t[j], fmaf(x1, w0x[j], fmaf(x2, w0y[j], w0bv[j])));
            unsigned qlo = __builtin_amdgcn_perm(__float_as_uint(fmaxf(h[1], 0.f)),
                                                 __float_as_uint(fmaxf(h[0], 0.f)), 0x07060302u);
            unsigned qhi = __builtin_amdgcn_perm(__float_as_uint(fmaxf(h[3], 0.f)),
                                                 __float_as_uint(fmaxf(h[2], 0.f)), 0x07060302u);
            int off = (r * 512 + c0 * 2) ^ ((r & 7) << 4);
            *(uint2*)((char*)h0s + off) = make_uint2(qlo, qhi);
        }
        __syncthreads();                                 // sync2: h0s ready
        // layer1: D = W1^T @ h0^T ; lane holds D[c=64w+16ct+4rg+i][sample=16rt+arow]
        f32x4 acc[2][4];
#pragma unroll
        for (int rt = 0; rt < 2; ++rt)
#pragma unroll
            for (int ct = 0; ct < 4; ++ct) acc[rt][ct] = (f32x4){0.f, 0.f, 0.f, 0.f};
#pragma unroll
        for (int kk = 0; kk < 8; ++kk) {
#pragma unroll
            for (int rt = 0; rt < 2; ++rt) {
                int row = rt * 16 + arow;
                int off = (row * 512 + kk * 64 + rg * 16) ^ ((row & 7) << 4);
                bf16x8 hf = *(const bf16x8*)((const char*)h0s + off);
                acc[rt][0] = __builtin_amdgcn_mfma_f32_16x16x32_bf16(afrag[kk][0], hf, acc[rt][0], 0, 0, 0);
                acc[rt][1] = __builtin_amdgcn_mfma_f32_16x16x32_bf16(afrag[kk][1], hf, acc[rt][1], 0, 0, 0);
                acc[rt][2] = __builtin_amdgcn_mfma_f32_16x16x32_bf16(afrag[kk][2], hf, acc[rt][2], 0, 0, 0);
                acc[rt][3] = __builtin_amdgcn_mfma_f32_16x16x32_bf16(afrag[kk][3], hf, acc[rt][3], 0, 0, 0);
            }
        }
        // layer2 epilogue: bias+relu, dot with w2 (lane-local over c), 2-step shfl over rg
#pragma unroll
        for (int rt = 0; rt < 2; ++rt) {
            float A0 = 0.f, A1 = 0.f;
#pragma unroll
            for (int ct = 0; ct < 4; ++ct) {
#pragma unroll
                for (int i = 0; i < 4; ++i) {
                    float v = fmaxf(acc[rt][ct][i] + b1v[ct][i], 0.f);
                    A0 = fmaf(v, w20v[ct][i], A0);
                    if (MLP) A1 = fmaf(v, w21v[ct][i], A1);
                }
            }
            A0 += __shfl_xor(A0, 16); A0 += __shfl_xor(A0, 32);
            if (MLP) { A1 += __shfl_xor(A1, 16); A1 += __shfl_xor(A1, 32); }
            if (rg == 0) {
                int row = rt * 16 + arow;
                red[w][row] = MLP ? fmaf(A1, dws1[sb][row], A0 * dws0[sb][row]) : A0;
            }
        }
        __syncthreads();                                 // sync3: red ready
        if (tid < TILE_M) {
            float s = red[0][tid] + red[1][tid] + red[2][tid] + red[3][tid];
            if (MLP) s += fmaf(b21, dws1[sb][tid], b20 * dws0[sb][tid]);
            else     s += b20;
            outp[rowbase + tid] = s;
        }
    }
}

// ---- loss: sum over r of (Y + Zdot - target)^2, /B ----
__global__ void loss_partial_kernel(const float* __restrict__ Yout, const float* __restrict__ fv,
                                    const float* __restrict__ zdot, float* __restrict__ partials) {
    __shared__ float wred[4];
    int tid = threadIdx.x;
    float s = 0.f;
    for (int r = blockIdx.x * 256 + tid; r < R_; r += gridDim.x * 256) {
        int n = r & (N_ - 1);
        float pred = Yout[r] + zdot[r];
        float target = (n == N_ - 1) ? fv[r >> 8] : Yout[r + 1];
        float d = pred - target;
        s = fmaf(d, d, s);
    }
#pragma unroll
    for (int m = 1; m < 64; m <<= 1) s += __shfl_xor(s, m);
    if ((tid & 63) == 0) wred[tid >> 6] = s;
    __syncthreads();
    if (tid == 0) partials[blockIdx.x] = wred[0] + wred[1] + wred[2] + wred[3];
}

__global__ void loss_final_kernel(const float* __restrict__ partials, float* __restrict__ out) {
    __shared__ float wred[4];
    int tid = threadIdx.x;
    float s = partials[tid] + partials[256 + tid] + partials[512 + tid] + partials[768 + tid];
#pragma unroll
    for (int m = 1; m < 64; m <<= 1) s += __shfl_xor(s, m);
    if ((tid & 63) == 0) wred[tid >> 6] = s;
    __syncthreads();
    if (tid == 0) out[0] = (wred[0] + wred[1] + wred[2] + wred[3]) * (1.0f / B_);
}

extern "C" void kernel_launch(void* const* d_in, const int* in_sizes, int n_in,
                              void* d_out, int out_size, void* d_ws, size_t ws_size,
                              hipStream_t stream) {
    const float* ts  = (const float*)d_in[0];
    const float* x0  = (const float*)d_in[1];
    const float* eps = (const float*)d_in[2];
    const float* fW0 = (const float*)d_in[3];
    const float* fb0 = (const float*)d_in[4];
    const float* fW1 = (const float*)d_in[5];
    const float* fb1 = (const float*)d_in[6];
    const float* fW2 = (const float*)d_in[7];
    const float* fb2 = (const float*)d_in[8];
    const float* gW0 = (const float*)d_in[9];
    const float* gb0 = (const float*)d_in[10];
    const float* gW1 = (const float*)d_in[11];
    const float* gb1 = (const float*)d_in[12];
    const float* gW2 = (const float*)d_in[13];
    const float* gb2 = (const float*)d_in[14];

    float* out  = (float*)d_out;
    float* Yout = out + 1;            // Y: (B,N,1) flat, row index r = b*N+n
    float* fv   = out + 1 + R_;       // final_value: (B,1)

    char* wsb = (char*)d_ws;
    float* xs            = (float*)wsb;                                         // B*N*2 f32 = 4MB
    unsigned short* wswz = (unsigned short*)(wsb + (4 << 20));                  // 256KB
    float* zdot          = (float*)(wsb + (4 << 20) + (256 << 10));             // 2MB
    float* partials      = (float*)(wsb + (4 << 20) + (256 << 10) + (2 << 20)); // 4KB

    hipLaunchKernelGGL(prep_weights, dim3(512), dim3(256), 0, stream, fW1, gW1, wswz);
    hipLaunchKernelGGL(traj_kernel, dim3(512), dim3(256), 0, stream, ts, x0, eps, xs, fv);
    hipLaunchKernelGGL(mlp_kernel<0>, dim3(GRID_MLP), dim3(256), 0, stream,
                       ts, eps, xs, wswz, fW0, fb0, fb1, fW2, fb2, Yout);
    hipLaunchKernelGGL(mlp_kernel<1>, dim3(GRID_MLP), dim3(256), 0, stream,
                       ts, eps, xs, wswz + 65536, gW0, gb0, gb1, gW2, gb2, zdot);
    hipLaunchKernelGGL(loss_partial_kernel, dim3(1024), dim3(256), 0, stream, Yout, fv, zdot, partials);
    hipLaunchKernelGGL(loss_final_kernel, dim3(1), dim3(256), 0, stream, partials, out);
}

// Round 6
// 200.432 us; speedup vs baseline: 1.1810x; 1.1810x over previous
//
#include <hip/hip_runtime.h>
#include <math.h>

#define B_ 2048
#define N_ 256
#define R_ (B_*N_)
#define MU_ 0.1f
#define SIGMA_ 0.2f
#define TILE_M 32
#define GRID_MLP 512
#define ITERS (R_ / TILE_M / GRID_MLP)   // 32

typedef __attribute__((ext_vector_type(8))) short bf16x8;
typedef __attribute__((ext_vector_type(4))) float f32x4;

__device__ __forceinline__ unsigned short f2bf(float x) {  // RNE (weights only)
    union { float f; unsigned u; } v; v.f = x;
    unsigned r = v.u + 0x7fffu + ((v.u >> 16) & 1u);
    return (unsigned short)(r >> 16);
}

// ---- convert fW1/gW1 (256x256 f32, k-major) to bf16 MFMA fragments ----
// short idx = ((kk*16 + ct)*64 + lane)*8 + j ; holds W1[k = kk*32+(lane>>4)*8+j][c = ct*16+(lane&15)]
__global__ void prep_weights(const float* __restrict__ fW1, const float* __restrict__ gW1,
                             unsigned short* __restrict__ wswz) {
    int idx = blockIdx.x * 256 + threadIdx.x;
    if (idx >= 2 * 65536) return;
    int m = idx >> 16, r = idx & 65535;
    int j = r & 7, lane = (r >> 3) & 63, frag = r >> 9;
    int kk = frag >> 4, ct = frag & 15;
    int k = kk * 32 + (lane >> 4) * 8 + j;
    int c = ct * 16 + (lane & 15);
    const float* W = m ? gW1 : fW1;
    wswz[idx] = f2bf(W[k * 256 + c]);
}

// ---- trajectory via wave-parallel prefix-product scan: one wave per batch row ----
__global__ void traj_kernel(const float* __restrict__ ts, const float* __restrict__ x0,
                            const float* __restrict__ eps, float* __restrict__ xs,
                            float* __restrict__ fv) {
    int gid = blockIdx.x * 256 + threadIdx.x;
    int b = gid >> 6, lane = gid & 63;
    int n0 = lane * 4;

    float t0 = ts[n0], t1 = ts[n0 + 1], t2 = ts[n0 + 2], t3 = ts[n0 + 3];
    float t4 = (n0 + 4 < N_) ? ts[n0 + 4] : t3;          // lane 63: h3 = 0
    float h0 = t1 - t0, h1 = t2 - t1, h2 = t3 - t2, h3 = t4 - t3;
    float s0 = sqrtf(h0), s1 = sqrtf(h1), s2 = sqrtf(h2), s3 = sqrtf(h3);

    const float4* e4 = (const float4*)(eps + (size_t)(b * N_ + n0) * 2);
    float4 ea = e4[0], eb = e4[1];
    float f0a = 1.f + MU_ * h0 + SIGMA_ * (ea.x * s0);
    float f0b = 1.f + MU_ * h0 + SIGMA_ * (ea.y * s0);
    float f1a = 1.f + MU_ * h1 + SIGMA_ * (ea.z * s1);
    float f1b = 1.f + MU_ * h1 + SIGMA_ * (ea.w * s1);
    float f2a = 1.f + MU_ * h2 + SIGMA_ * (eb.x * s2);
    float f2b = 1.f + MU_ * h2 + SIGMA_ * (eb.y * s2);
    float f3a = 1.f + MU_ * h3 + SIGMA_ * (eb.z * s3);
    float f3b = 1.f + MU_ * h3 + SIGMA_ * (eb.w * s3);

    float Pa = f0a * f1a * f2a * f3a;
    float Pb = f0b * f1b * f2b * f3b;
    float Sa = Pa, Sb = Pb;
#pragma unroll
    for (int d = 1; d < 64; d <<= 1) {
        float va = __shfl_up(Sa, d);
        float vb = __shfl_up(Sb, d);
        if (lane >= d) { Sa *= va; Sb *= vb; }
    }
    float Ea = __shfl_up(Sa, 1);
    float Eb = __shfl_up(Sb, 1);
    if (lane == 0) { Ea = 1.f; Eb = 1.f; }

    float x0a = x0[2 * b], x0b = x0[2 * b + 1];
    float xa0 = x0a * Ea, xb0 = x0b * Eb;
    float xa1 = xa0 * f0a, xb1 = xb0 * f0b;
    float xa2 = xa1 * f1a, xb2 = xb1 * f1b;
    float xa3 = xa2 * f2a, xb3 = xb2 * f2b;

    float4* xsv = (float4*)(xs + (size_t)(b * N_ + n0) * 2);
    xsv[0] = make_float4(xa0, xb0, xa1, xb1);
    xsv[1] = make_float4(xa2, xb2, xa3, xb3);
    if (lane == 63) fv[b] = xa3 * xa3 + xb3 * xb3;
}

// ---- fused MLP, transposed GEMM: D = W1^T(A, resident regs) @ h0^T(B, LDS) ----
// 512 threads / 8 waves; wave w owns cols [32w, 32w+32) -> afrag only 64 VGPRs.
// Live set sized to fit the allocator's observed 128-VGPR ceiling (r4/r5 evidence:
// requesting more via launch_bounds/waves_per_eu does NOT lift it; excess spills).
template<int MLP>
__global__ __launch_bounds__(512) void mlp_kernel(
        const float* __restrict__ ts, const float* __restrict__ eps, const float* __restrict__ xs,
        const unsigned short* __restrict__ wswz,
        const float* __restrict__ W0, const float* __restrict__ b0,
        const float* __restrict__ b1, const float* __restrict__ W2, const float* __restrict__ b2,
        float* __restrict__ outp) {

    __shared__ __align__(16) unsigned short h0s[TILE_M * 256];   // 16KB, XOR-swizzled rows
    __shared__ float tss[2][TILE_M], txs1[2][TILE_M], txs2[2][TILE_M];
    __shared__ float dws0[2][TILE_M], dws1[2][TILE_M];
    __shared__ float red[8][TILE_M];
    __shared__ __align__(16) float sh_b1[256], sh_w20[256], sh_w21[256];

    const int tid  = threadIdx.x;
    const int lane = tid & 63;
    const int w    = tid >> 6;       // wave 0..7: cols [32w, 32w+32)
    const int arow = lane & 15;      // sample index within 16-tile
    const int rg   = lane >> 4;      // k-group / c-subgroup

    // layer0: this thread computes cols [c0,c0+4) for rows [4w, 4w+4)
    const int c0 = (tid & 63) * 4;
    const int row0 = (tid >> 6) * 4;
    f32x4 w0t = *(const f32x4*)(W0 + c0);
    f32x4 w0x = *(const f32x4*)(W0 + 256 + c0);
    f32x4 w0y = *(const f32x4*)(W0 + 512 + c0);
    f32x4 w0bv = *(const f32x4*)(b0 + c0);

    // stage b1 / W2 columns into LDS (read per-tile; keeps them out of the live set)
    if (tid < 256) {
        sh_b1[tid] = b1[tid];
        if (MLP) { sh_w20[tid] = W2[2 * tid]; sh_w21[tid] = W2[2 * tid + 1]; }
        else     { sh_w20[tid] = W2[tid];     sh_w21[tid] = 0.f; }
    }
    const float b20 = b2[0];
    const float b21 = MLP ? b2[1] : 0.f;

    // resident A-fragments of W1^T: 8 kk x 2 ct x 4 VGPR = 64 VGPRs
    bf16x8 afrag[8][2];
    const bf16x8* wsw8 = (const bf16x8*)wswz;
#pragma unroll
    for (int kk = 0; kk < 8; ++kk)
#pragma unroll
        for (int p = 0; p < 2; ++p)
            afrag[kk][p] = wsw8[(kk * 16 + (w * 2 + p)) * 64 + lane];

    // prefetch tile 0 stage data
    float p_x1 = 0.f, p_x2 = 0.f, p_t = 0.f, p_tn = 0.f, p_e0 = 0.f, p_e1 = 0.f;
    if (tid < TILE_M) {
        int r = blockIdx.x * TILE_M + tid, n = r & (N_ - 1);
        float2 xv = ((const float2*)xs)[r];
        p_x1 = xv.x; p_x2 = xv.y;
        p_t = ts[n]; p_tn = (n < N_ - 1) ? ts[n + 1] : ts[n];
        if (MLP) { float2 ev = ((const float2*)eps)[r]; p_e0 = ev.x; p_e1 = ev.y; }
    }

    for (int it = 0; it < ITERS; ++it) {
        const int rowbase = (blockIdx.x + it * GRID_MLP) * TILE_M;
        const int sb = it & 1;
        if (tid < TILE_M) {
            tss[sb][tid] = p_t; txs1[sb][tid] = p_x1; txs2[sb][tid] = p_x2;
            if (MLP) {
                float sdt = sqrtf(p_tn - p_t);
                dws0[sb][tid] = p_e0 * sdt; dws1[sb][tid] = p_e1 * sdt;
            }
        }
        __syncthreads();                                 // sync1: stage[sb] visible
        if (tid < TILE_M && it + 1 < ITERS) {            // prefetch next tile
            int r = rowbase + GRID_MLP * TILE_M + tid, n = r & (N_ - 1);
            float2 xv = ((const float2*)xs)[r];
            p_x1 = xv.x; p_x2 = xv.y;
            p_t = ts[n]; p_tn = (n < N_ - 1) ? ts[n + 1] : ts[n];
            if (MLP) { float2 ev = ((const float2*)eps)[r]; p_e0 = ev.x; p_e1 = ev.y; }
        }
        // layer0: 4 rows x 4 cols per thread, truncation-pack to bf16
#pragma unroll
        for (int ii = 0; ii < 4; ++ii) {
            int r = row0 + ii;
            float t = tss[sb][r], x1 = txs1[sb][r], x2 = txs2[sb][r];
            f32x4 h;
#pragma unroll
            for (int j = 0; j < 4; ++j)
                h[j] = fmaf(t, w0t[j], fmaf(x1, w0x[j], fmaf(x2, w0y[j], w0bv[j])));
            unsigned qlo = __builtin_amdgcn_perm(__float_as_uint(fmaxf(h[1], 0.f)),
                                                 __float_as_uint(fmaxf(h[0], 0.f)), 0x07060302u);
            unsigned qhi = __builtin_amdgcn_perm(__float_as_uint(fmaxf(h[3], 0.f)),
                                                 __float_as_uint(fmaxf(h[2], 0.f)), 0x07060302u);
            int off = (r * 512 + c0 * 2) ^ ((r & 7) << 4);
            *(uint2*)((char*)h0s + off) = make_uint2(qlo, qhi);
        }
        __syncthreads();                                 // sync2: h0s ready
        // layer1: D = W1^T @ h0^T ; lane holds D[c=32w+16p+4rg+i][sample=16rt+arow]
        // acc initialized with b1 (MFMA C-operand) so no epilogue bias add
        f32x4 acc[2][2];
        {
            f32x4 bi0 = *(const f32x4*)&sh_b1[w * 32 + 4 * rg];
            f32x4 bi1 = *(const f32x4*)&sh_b1[w * 32 + 16 + 4 * rg];
            acc[0][0] = bi0; acc[1][0] = bi0;
            acc[0][1] = bi1; acc[1][1] = bi1;
        }
#pragma unroll
        for (int kk = 0; kk < 8; ++kk) {
#pragma unroll
            for (int rt = 0; rt < 2; ++rt) {
                int row = rt * 16 + arow;
                int off = (row * 512 + kk * 64 + rg * 16) ^ ((row & 7) << 4);
                bf16x8 hf = *(const bf16x8*)((const char*)h0s + off);
                acc[rt][0] = __builtin_amdgcn_mfma_f32_16x16x32_bf16(afrag[kk][0], hf, acc[rt][0], 0, 0, 0);
                acc[rt][1] = __builtin_amdgcn_mfma_f32_16x16x32_bf16(afrag[kk][1], hf, acc[rt][1], 0, 0, 0);
            }
        }
        // layer2 epilogue: relu, dot with w2 (from LDS), 2-step shfl over rg, cross-wave via red
        float A0[2] = {0.f, 0.f}, A1[2] = {0.f, 0.f};
#pragma unroll
        for (int p = 0; p < 2; ++p) {
            f32x4 w20v = *(const f32x4*)&sh_w20[w * 32 + p * 16 + 4 * rg];
            f32x4 w21v;
            if (MLP) w21v = *(const f32x4*)&sh_w21[w * 32 + p * 16 + 4 * rg];
#pragma unroll
            for (int rt = 0; rt < 2; ++rt) {
#pragma unroll
                for (int i = 0; i < 4; ++i) {
                    float v = fmaxf(acc[rt][p][i], 0.f);
                    A0[rt] = fmaf(v, w20v[i], A0[rt]);
                    if (MLP) A1[rt] = fmaf(v, w21v[i], A1[rt]);
                }
            }
        }
#pragma unroll
        for (int rt = 0; rt < 2; ++rt) {
            A0[rt] += __shfl_xor(A0[rt], 16); A0[rt] += __shfl_xor(A0[rt], 32);
            if (MLP) { A1[rt] += __shfl_xor(A1[rt], 16); A1[rt] += __shfl_xor(A1[rt], 32); }
            if (rg == 0) {
                int row = rt * 16 + arow;
                red[w][row] = MLP ? fmaf(A1[rt], dws1[sb][row], A0[rt] * dws0[sb][row]) : A0[rt];
            }
        }
        __syncthreads();                                 // sync3: red ready
        if (tid < TILE_M) {
            float s = red[0][tid] + red[1][tid] + red[2][tid] + red[3][tid]
                    + red[4][tid] + red[5][tid] + red[6][tid] + red[7][tid];
            if (MLP) s += fmaf(b21, dws1[sb][tid], b20 * dws0[sb][tid]);
            else     s += b20;
            outp[rowbase + tid] = s;
        }
    }
}

// ---- loss: sum over r of (Y + Zdot - target)^2, /B ----
__global__ void loss_partial_kernel(const float* __restrict__ Yout, const float* __restrict__ fv,
                                    const float* __restrict__ zdot, float* __restrict__ partials) {
    __shared__ float wred[4];
    int tid = threadIdx.x;
    float s = 0.f;
    for (int r = blockIdx.x * 256 + tid; r < R_; r += gridDim.x * 256) {
        int n = r & (N_ - 1);
        float pred = Yout[r] + zdot[r];
        float target = (n == N_ - 1) ? fv[r >> 8] : Yout[r + 1];
        float d = pred - target;
        s = fmaf(d, d, s);
    }
#pragma unroll
    for (int m = 1; m < 64; m <<= 1) s += __shfl_xor(s, m);
    if ((tid & 63) == 0) wred[tid >> 6] = s;
    __syncthreads();
    if (tid == 0) partials[blockIdx.x] = wred[0] + wred[1] + wred[2] + wred[3];
}

__global__ void loss_final_kernel(const float* __restrict__ partials, float* __restrict__ out) {
    __shared__ float wred[4];
    int tid = threadIdx.x;
    float s = partials[tid] + partials[256 + tid] + partials[512 + tid] + partials[768 + tid];
#pragma unroll
    for (int m = 1; m < 64; m <<= 1) s += __shfl_xor(s, m);
    if ((tid & 63) == 0) wred[tid >> 6] = s;
    __syncthreads();
    if (tid == 0) out[0] = (wred[0] + wred[1] + wred[2] + wred[3]) * (1.0f / B_);
}

extern "C" void kernel_launch(void* const* d_in, const int* in_sizes, int n_in,
                              void* d_out, int out_size, void* d_ws, size_t ws_size,
                              hipStream_t stream) {
    const float* ts  = (const float*)d_in[0];
    const float* x0  = (const float*)d_in[1];
    const float* eps = (const float*)d_in[2];
    const float* fW0 = (const float*)d_in[3];
    const float* fb0 = (const float*)d_in[4];
    const float* fW1 = (const float*)d_in[5];
    const float* fb1 = (const float*)d_in[6];
    const float* fW2 = (const float*)d_in[7];
    const float* fb2 = (const float*)d_in[8];
    const float* gW0 = (const float*)d_in[9];
    const float* gb0 = (const float*)d_in[10];
    const float* gW1 = (const float*)d_in[11];
    const float* gb1 = (const float*)d_in[12];
    const float* gW2 = (const float*)d_in[13];
    const float* gb2 = (const float*)d_in[14];

    float* out  = (float*)d_out;
    float* Yout = out + 1;            // Y: (B,N,1) flat, row index r = b*N+n
    float* fv   = out + 1 + R_;       // final_value: (B,1)

    char* wsb = (char*)d_ws;
    float* xs            = (float*)wsb;                                         // B*N*2 f32 = 4MB
    unsigned short* wswz = (unsigned short*)(wsb + (4 << 20));                  // 256KB
    float* zdot          = (float*)(wsb + (4 << 20) + (256 << 10));             // 2MB
    float* partials      = (float*)(wsb + (4 << 20) + (256 << 10) + (2 << 20)); // 4KB

    hipLaunchKernelGGL(prep_weights, dim3(512), dim3(256), 0, stream, fW1, gW1, wswz);
    hipLaunchKernelGGL(traj_kernel, dim3(512), dim3(256), 0, stream, ts, x0, eps, xs, fv);
    hipLaunchKernelGGL(mlp_kernel<0>, dim3(GRID_MLP), dim3(512), 0, stream,
                       ts, eps, xs, wswz, fW0, fb0, fb1, fW2, fb2, Yout);
    hipLaunchKernelGGL(mlp_kernel<1>, dim3(GRID_MLP), dim3(512), 0, stream,
                       ts, eps, xs, wswz + 65536, gW0, gb0, gb1, gW2, gb2, zdot);
    hipLaunchKernelGGL(loss_partial_kernel, dim3(1024), dim3(256), 0, stream, Yout, fv, zdot, partials);
    hipLaunchKernelGGL(loss_final_kernel, dim3(1), dim3(256), 0, stream, partials, out);
}